// Round 13
// baseline (393.202 us; speedup 1.0000x reference)
//
#include <hip/hip_runtime.h>
#include <hip/hip_bf16.h>
#include <stdint.h>

#define DFEAT 256
#define NPTS  8192

typedef __attribute__((ext_vector_type(8)))  short bf16x8;   // 8 bf16 = 4 VGPRs
typedef __attribute__((ext_vector_type(16))) float f32x16;   // 32x32 C/D
typedef __attribute__((ext_vector_type(4)))  int   int4v;
typedef __attribute__((ext_vector_type(4)))  float f32x4;
typedef __attribute__((ext_vector_type(8)))  float f32x8;
typedef __attribute__((ext_vector_type(8)))  _Float16 f16x8;

#define AS1 __attribute__((address_space(1)))
#define AS3 __attribute__((address_space(3)))

__device__ inline void dma16(const void* g, void* l) {
  // async global->LDS, 16B/lane; LDS dest = wave-uniform base + lane*16
  __builtin_amdgcn_global_load_lds((const AS1 uint32_t*)g, (AS3 uint32_t*)l, 16, 0, 0);
}

__device__ inline uint16_t f2bf(float f) {  // RNE fp32->bf16
  union { float f; uint32_t u; } v; v.f = f;
  return (uint16_t)((v.u + 0x7FFFu + ((v.u >> 16) & 1u)) >> 16);
}

// ---------------------------------------------------------------------------
// ws fragment layouts (written by ms_combine):
//  xaf: per 32-point block nb, chunk s, lane: X[d=s*8..+8][pt=nb*32+lane]
//       byte addr = nb*16384 + s*512 + lane*16.     (4 MB)
//  xbf: per 32-d block db, chunk u (n/8), lane: X[d=db*32+lane][n=u*8..+8]
//       byte addr = db*524288 + u*512 + lane*16.    (4 MB)
//  num_p[4][256][8192] _Float16 (16MB): q-slab, plain stores, single writer.
//  cs_p[8][8192] f32: slice 2q+a_sub, plain stores, single writer.
//
// R13 delta on R11/R12 (296.4us; fused 79.3):
//  - T5 s_setprio(1/0) around the S and PV MFMA clusters. Pipe accounting:
//    MFMA 35%, L2 39%, VALU 22%, LDS 20% -- nothing saturated; the limiter
//    is imperfect overlap between the 2 co-resident WGs. setprio lets the
//    CU scheduler favor the WG in its MFMA phase over the other WG's
//    exp/load phase (m191 regime: independent wave-groups, +4-7%).
//  - S 2-way split reverted (R12: null, chain is not the pole; -16 VGPR).
// K-loop otherwise identical to R11: single-barrier pipelined body, dual
// top-of-body VMEM prefetch, counted vmcnt(8), Ps dbuf, v_exp_f32 exp,
// cvt_pk packing, XCD-pair blockIdx swizzle, f16 partial slabs.
// ---------------------------------------------------------------------------
__global__ __launch_bounds__(256, 2) void ms_fused(
    const uint16_t* __restrict__ xaf,
    const uint16_t* __restrict__ xbf,
    _Float16* __restrict__ nump,       // [4][256][8192] f16 partial slabs
    float* __restrict__ csp)           // [8][8192] f32 partial slices
{
  __shared__ __attribute__((aligned(16))) uint16_t XT[2][16384];  // 64KB stage
  __shared__ __attribute__((aligned(16))) uint16_t Ps[2][4096];   // 2x8KB dbuf

  const int tid  = threadIdx.x;
  const int w    = tid >> 6;
  const int lane = tid & 63;
  const int l31  = lane & 31;
  const int g    = lane >> 5;
  const int bid  = blockIdx.x;
  const int mt   = (bid & 1) | ((bid >> 3) << 1);   // 0..127
  const int q    = (bid >> 1) & 3;                  // n-split 0..3
  const int m0   = mt * 64;
  const int a_sub = w >> 1;                  // S n-sub (0/1)
  const int b_sub = w & 1;                   // S m-sub (0/1)

  const char* xafc = (const char*)xaf;
  const char* xbfc = (const char*)xbf;
  char*       XTc  = (char*)XT;
  char*       Psc  = (char*)Ps;

  // Xm B-fragments resident (64 VGPRs), one-time coalesced load
  bf16x8 Bm[16];
  {
    const char* bp = xafc + (size_t)(m0 / 32 + b_sub) * 16384 + g * 512 + l31 * 16;
    #pragma unroll
    for (int ks = 0; ks < 16; ++ks)
      Bm[ks] = __builtin_bit_cast(bf16x8, *(const int4v*)(bp + ks * 1024));
  }

  f32x16 accO[2][2];
  #pragma unroll
  for (int i = 0; i < 2; ++i)
    #pragma unroll
    for (int j = 0; j < 2; ++j)
      #pragma unroll
      for (int r = 0; r < 16; ++r) accO[i][j][r] = 0.0f;
  float csacc = 0.0f;

  const int mloc = 32 * b_sub + l31;
  const int l7   = l31 & 7;
  const int j0   = q * 32;                   // first n-tile index

  // prologue: stage tile j0 into XT[0] (identity copy, 8x 16B per thread)
  {
    const char* src = xafc + (size_t)j0 * 32768;
    #pragma unroll
    for (int r = 0; r < 8; ++r)
      dma16(src + tid * 16 + r * 4096, XTc + tid * 16 + r * 4096);
  }
  __syncthreads();   // one-time full drain; XT[0] ready

  bf16x8 XfE[2][4], XfO[2][4];   // ping-pong PV A-frag buffers

// body T_: cur=CUR_ (=T_&1), loads Xf(T_) into XF_LD, PV(T_-1) uses XF_USE
#define MS_BODY(T_, CUR_, XF_LD, XF_USE, DO_PV)                               \
  {                                                                           \
    const int jt_ = j0 + (T_);                                                \
    char*       psW_ = Psc + (CUR_) * 8192;                                   \
    const char* psR_ = Psc + ((CUR_) ^ 1) * 8192;                             \
    /* issue DMA(t+1) -> XT[cur^1] (freed at bar(t-1)) */                     \
    if ((T_) < 31) {                                                          \
      const char* src_ = xafc + (size_t)(jt_ + 1) * 32768;                    \
      _Pragma("unroll")                                                       \
      for (int r = 0; r < 8; ++r)                                             \
        dma16(src_ + tid * 16 + r * 4096,                                     \
              XTc + ((CUR_) ^ 1) * 32768 + tid * 16 + r * 4096);              \
    }                                                                         \
    /* issue Xf(t) (consumed by PV in body t+1) */                            \
    {                                                                         \
      const int n0_ = jt_ * 64;                                               \
      _Pragma("unroll")                                                       \
      for (int t2 = 0; t2 < 2; ++t2) {                                        \
        const char* xp_ = xbfc + (size_t)(2 * w + t2) * 524288 +              \
                          (size_t)(n0_ >> 3) * 512 + g * 512 + l31 * 16;      \
        _Pragma("unroll")                                                     \
        for (int ks = 0; ks < 4; ++ks)                                        \
          XF_LD[t2][ks] =                                                     \
              __builtin_bit_cast(bf16x8, *(const int4v*)(xp_ + ks * 1024));   \
      }                                                                       \
    }                                                                         \
    /* VMEM pinned above this point; ALU/MFMA/DS may cross freely */          \
    __builtin_amdgcn_sched_barrier(0x38F);                                    \
    /* ---- S(t) = Xn^T Xm from XT[cur]; setprio(1) favors this WG's ----     \
       MFMA cluster over the other WG's exp/load phase (T5) */                \
    f32x16 s;                                                                 \
    _Pragma("unroll")                                                         \
    for (int r = 0; r < 16; ++r) s[r] = 0.0f;                                 \
    __builtin_amdgcn_s_setprio(1);                                            \
    {                                                                         \
      const char* ap_ = XTc + (CUR_) * 32768 + a_sub * 16384 + g * 512 +      \
                        l31 * 16;                                             \
      _Pragma("unroll")                                                       \
      for (int ks = 0; ks < 16; ++ks) {                                       \
        bf16x8 A = __builtin_bit_cast(bf16x8,                                 \
                                      *(const int4v*)(ap_ + ks * 1024));      \
        s = __builtin_amdgcn_mfma_f32_32x32x16_bf16(A, Bm[ks], s, 0, 0, 0);   \
      }                                                                       \
    }                                                                         \
    __builtin_amdgcn_s_setprio(0);                                            \
    /* ---- PV(t-1): O += Xn(t-1) * P(t-1) ---- */                            \
    if (DO_PV) {                                                              \
      __builtin_amdgcn_s_setprio(1);                                          \
      _Pragma("unroll")                                                       \
      for (int ks = 0; ks < 4; ++ks) {                                        \
        bf16x8 Bp[2];                                                         \
        _Pragma("unroll")                                                     \
        for (int mm = 0; mm < 2; ++mm) {                                      \
          int mrow = 32 * mm + l31;                                           \
          int p = (2 * ks + g) ^ l7;                                          \
          Bp[mm] = __builtin_bit_cast(bf16x8,                                 \
              *(const int4v*)(psR_ + mrow * 128 + p * 16));                   \
        }                                                                     \
        _Pragma("unroll")                                                     \
        for (int t2 = 0; t2 < 2; ++t2) {                                      \
          accO[t2][0] = __builtin_amdgcn_mfma_f32_32x32x16_bf16(              \
              XF_USE[t2][ks], Bp[0], accO[t2][0], 0, 0, 0);                   \
          accO[t2][1] = __builtin_amdgcn_mfma_f32_32x32x16_bf16(              \
              XF_USE[t2][ks], Bp[1], accO[t2][1], 0, 0, 0);                   \
        }                                                                     \
      }                                                                       \
      __builtin_amdgcn_s_setprio(0);                                          \
    }                                                                         \
    /* ---- exp(t) -> Ps[cur]: e^(6s) = v_exp_f32(8.6562*s) ---- */           \
    _Pragma("unroll")                                                         \
    for (int k = 0; k < 4; ++k) {                                             \
      float a0 = 8.65617024533378f * s[4 * k + 0];                            \
      float a1 = 8.65617024533378f * s[4 * k + 1];                            \
      float a2 = 8.65617024533378f * s[4 * k + 2];                            \
      float a3 = 8.65617024533378f * s[4 * k + 3];                            \
      float e0, e1, e2, e3;                                                   \
      asm("v_exp_f32 %0, %1" : "=v"(e0) : "v"(a0));                           \
      asm("v_exp_f32 %0, %1" : "=v"(e1) : "v"(a1));                           \
      asm("v_exp_f32 %0, %1" : "=v"(e2) : "v"(a2));                           \
      asm("v_exp_f32 %0, %1" : "=v"(e3) : "v"(a3));                           \
      csacc += (e0 + e1) + (e2 + e3);                                         \
      uint32_t lo, hi;                                                        \
      asm("v_cvt_pk_bf16_f32 %0, %1, %2" : "=v"(lo) : "v"(e0), "v"(e1));      \
      asm("v_cvt_pk_bf16_f32 %0, %1, %2" : "=v"(hi) : "v"(e2), "v"(e3));      \
      int p = (4 * a_sub + k) ^ (mloc & 7);                                   \
      *(uint64_t*)(psW_ + mloc * 128 + p * 16 + 8 * g) =                      \
          ((uint64_t)hi << 32) | lo;                                          \
    }                                                                         \
    /* bar(t): Ps[cur] visible; DMA(t+1) (oldest 8) done; Xf(t) flies */      \
    asm volatile("s_waitcnt vmcnt(8) lgkmcnt(0)" ::: "memory");               \
    __builtin_amdgcn_s_barrier();                                             \
  }

  MS_BODY(0, 0, XfE, XfO, false)
  for (int tp = 0; tp < 15; ++tp) {
    const int tb = 2 * tp;
    MS_BODY(tb + 1, 1, XfO, XfE, true)
    MS_BODY(tb + 2, 0, XfE, XfO, true)
  }
  MS_BODY(31, 1, XfO, XfE, true)
#undef MS_BODY

  // ---- final PV(31): P from Ps[1] (written by body 31), Xf(31)=XfO ----
  {
    const char* psR = Psc + 8192;
    #pragma unroll
    for (int ks = 0; ks < 4; ++ks) {
      bf16x8 Bp[2];
      #pragma unroll
      for (int mm = 0; mm < 2; ++mm) {
        int mrow = 32 * mm + l31;
        int p = (2 * ks + g) ^ l7;
        Bp[mm] = __builtin_bit_cast(bf16x8,
            *(const int4v*)(psR + mrow * 128 + p * 16));
      }
      #pragma unroll
      for (int t2 = 0; t2 < 2; ++t2) {
        accO[t2][0] = __builtin_amdgcn_mfma_f32_32x32x16_bf16(XfO[t2][ks], Bp[0], accO[t2][0], 0,0,0);
        accO[t2][1] = __builtin_amdgcn_mfma_f32_32x32x16_bf16(XfO[t2][ks], Bp[1], accO[t2][1], 0,0,0);
      }
    }
  }

  // ---- epilogue: PLAIN f16 stores into private q-slab (single writer) ----
  csacc += __shfl_xor(csacc, 32, 64);
  if (g == 0) csp[(size_t)(2 * q + a_sub) * NPTS + m0 + mloc] = csacc;
  {
    _Float16* np = nump + (size_t)q * (DFEAT * (size_t)NPTS);
    #pragma unroll
    for (int t2 = 0; t2 < 2; ++t2)
      #pragma unroll
      for (int mm = 0; mm < 2; ++mm)
        #pragma unroll
        for (int r = 0; r < 16; ++r) {
          int drow = 32 * (2 * w + t2) + (r & 3) + 8 * (r >> 2) + 4 * g;
          int mg   = m0 + 32 * mm + l31;
          np[(size_t)drow * NPTS + mg] = (_Float16)accO[t2][mm][r];
        }
  }
}

// ---------------------------------------------------------------------------
// Combine. mode1: v = (sum of 4 f16 num_p slabs) * (1 / sum of 8 cs_p)
//          -> yout ; mode0: v = srcX (initial fp32 X).
// 8-wide lanes: 16B f16x8 slab loads, f32 summation, 32B f32x8 yout store.
// last=1: yout only (skip LDS transpose + frag emission entirely).
// ---------------------------------------------------------------------------
__global__ __launch_bounds__(256) void ms_combine(
    const float* __restrict__ srcX, const _Float16* __restrict__ nh,
    const float* __restrict__ csp, float* __restrict__ yout,
    uint16_t* __restrict__ xaf, uint16_t* __restrict__ xbf,
    const int mode, const int last)
{
  __shared__ uint16_t T[64][66];
  const int tid = threadIdx.x;
  const int n0 = blockIdx.x * 64;
  const int d0 = blockIdx.y * 64;

  f32x8 rinv;
  if (mode) {
    const int mq = tid & 7;
    f32x8 c = *(const f32x8*)(csp + n0 + mq * 8);
    #pragma unroll
    for (int s2 = 1; s2 < 8; ++s2)
      c += *(const f32x8*)(csp + (size_t)s2 * NPTS + n0 + mq * 8);
    #pragma unroll
    for (int k = 0; k < 8; ++k) rinv[k] = 1.0f / c[k];
  }

  #pragma unroll
  for (int i = 0; i < 2; ++i) {
    int e  = tid + i * 256;              // 0..511: (dl, mq) 8-float slot
    int dl = e >> 3, mq = e & 7;
    size_t idx = (size_t)(d0 + dl) * NPTS + n0 + mq * 8;
    f32x8 v;
    if (mode) {
      const size_t SS = (size_t)DFEAT * NPTS;   // slab stride (elements)
      f16x8 a0 = *(const f16x8*)(nh + idx);
      f16x8 a1 = *(const f16x8*)(nh + idx + SS);
      f16x8 a2 = *(const f16x8*)(nh + idx + 2 * SS);
      f16x8 a3 = *(const f16x8*)(nh + idx + 3 * SS);
      v = (__builtin_convertvector(a0, f32x8) +
           __builtin_convertvector(a1, f32x8)) +
          (__builtin_convertvector(a2, f32x8) +
           __builtin_convertvector(a3, f32x8));
      v *= rinv;
      *(f32x8*)(yout + idx) = v;
    } else {
      v = *(const f32x8*)(srcX + idx);
    }
    if (!last) {
      #pragma unroll
      for (int k = 0; k < 8; ++k) T[dl][mq * 8 + k] = f2bf(v[k]);
    }
  }
  if (last) return;
  __syncthreads();

  char* xafc = (char*)xaf;
  char* xbfc = (char*)xbf;
  // xaf chunks: (nb, s, lane) -> T[s*8 + j][nb*32+lane]
  #pragma unroll
  for (int i = 0; i < 2; ++i) {
    int c  = tid + i * 256;
    int nb = c >> 8, s2 = (c >> 5) & 7, ln = c & 31;
    union { uint32_t u[4]; int4v v; } pk;
    #pragma unroll
    for (int k = 0; k < 4; ++k) {
      uint32_t lo = T[s2 * 8 + 2 * k][nb * 32 + ln];
      uint32_t hi = T[s2 * 8 + 2 * k + 1][nb * 32 + ln];
      pk.u[k] = lo | (hi << 16);
    }
    *(int4v*)(xafc + (size_t)(n0 / 32 + nb) * 16384 +
              (size_t)(d0 / 8 + s2) * 512 + ln * 16) = pk.v;
  }
  // xbf chunks: (db, u, lane) -> T[db*32+lane][u*8 + j]  (row-contiguous)
  #pragma unroll
  for (int i = 0; i < 2; ++i) {
    int c  = tid + i * 256;
    int db = c >> 8, uu = (c >> 5) & 7, ln = c & 31;
    const uint16_t* tr = &T[db * 32 + ln][uu * 8];
    union { uint32_t u[4]; int4v v; } pk;
    #pragma unroll
    for (int k = 0; k < 4; ++k)
      pk.u[k] = (uint32_t)tr[2 * k] | ((uint32_t)tr[2 * k + 1] << 16);
    *(int4v*)(xbfc + (size_t)(d0 / 32 + db) * 524288 +
              (size_t)(n0 / 8 + uu) * 512 + ln * 16) = pk.v;
  }
}

extern "C" void kernel_launch(void* const* d_in, const int* in_sizes, int n_in,
                              void* d_out, int out_size, void* d_ws, size_t ws_size,
                              hipStream_t stream)
{
  (void)in_sizes; (void)n_in; (void)out_size; (void)ws_size;
  const float* X = (const float*)d_in[0];
  float* out = (float*)d_out;
  char* ws = (char*)d_ws;
  // ws: [0,4M) xaf ; [4M,8M) xbf ; [8M,24M) num_p[4] f16 ; [24M,+256K) cs_p[8]
  uint16_t* xaf  = (uint16_t*)(ws);
  uint16_t* xbf  = (uint16_t*)(ws + (4u << 20));
  _Float16* nump = (_Float16*)(ws + (8u << 20));
  float*    csp  = (float*)   (ws + (24u << 20));

  // no zeroing needed: every partial element is written by exactly one
  // thread each iteration before combine reads it.

  dim3 cgrid(NPTS / 64, DFEAT / 64);
  ms_combine<<<cgrid, 256, 0, stream>>>(X, nullptr, nullptr, nullptr,
                                        xaf, xbf, 0, 0);
  for (int it = 0; it < 3; ++it) {
    ms_fused<<<512, 256, 0, stream>>>(xaf, xbf, nump, csp);
    ms_combine<<<cgrid, 256, 0, stream>>>(nullptr, nump, csp,
                                          out + (size_t)it * DFEAT * NPTS,
                                          xaf, xbf, 1, it == 2);
  }
}

// Round 14
// 295.562 us; speedup vs baseline: 1.3304x; 1.3304x over previous
//
#include <hip/hip_runtime.h>
#include <hip/hip_bf16.h>
#include <stdint.h>

#define DFEAT 256
#define NPTS  8192

typedef __attribute__((ext_vector_type(8)))  short bf16x8;   // 8 bf16 = 4 VGPRs
typedef __attribute__((ext_vector_type(16))) float f32x16;   // 32x32 C/D
typedef __attribute__((ext_vector_type(4)))  int   int4v;
typedef __attribute__((ext_vector_type(4)))  float f32x4;
typedef __attribute__((ext_vector_type(8)))  float f32x8;
typedef __attribute__((ext_vector_type(8)))  _Float16 f16x8;

#define AS1 __attribute__((address_space(1)))
#define AS3 __attribute__((address_space(3)))

__device__ inline void dma16(const void* g, void* l) {
  // async global->LDS, 16B/lane; LDS dest = wave-uniform base + lane*16
  __builtin_amdgcn_global_load_lds((const AS1 uint32_t*)g, (AS3 uint32_t*)l, 16, 0, 0);
}

__device__ inline uint16_t f2bf(float f) {  // RNE fp32->bf16
  union { float f; uint32_t u; } v; v.f = f;
  return (uint16_t)((v.u + 0x7FFFu + ((v.u >> 16) & 1u)) >> 16);
}

// ---------------------------------------------------------------------------
// ws fragment layouts (written by ms_combine):
//  xaf: per 32-point block nb, chunk s, lane: X[d=s*8..+8][pt=nb*32+lane]
//       byte addr = nb*16384 + s*512 + lane*16.     (4 MB)
//  xbf: per 32-d block db, chunk u (n/8), lane: X[d=db*32+lane][n=u*8..+8]
//       byte addr = db*524288 + u*512 + lane*16.    (4 MB)
//  num_p[4][256][8192] _Float16 (16MB): q-slab, plain stores, single writer.
//  cs_p[8][8192] f32: slice 2q+a_sub, plain stores, single writer.
//
// R14 = verified-best composition: R11's fused (79.3us) + R12's combine.
// R13's setprio REVERTED: the intrinsic pairs acted as code-motion barriers,
// register pressure crossed the cap, accO spilled to scratch (WRITE 16.6->
// 55MB, FETCH 14.4->48.6MB, fused 79->120us). T5 is structure-hostile here.
// Probe ledger: wins = {single-barrier pipelined body, dual top-of-body
// prefetch, counted vmcnt(8), private q-slabs, f16 slabs, v_exp asm,
// cvt_pk packing, XCD-pair swizzle}; nulls = {S chain splits, reg staging,
// barrier-flavor variants, combine widening}; regressions = {3WG occupancy,
// single-buffer XT, cross-WG fence fusion, exp2f libm, setprio}.
// ---------------------------------------------------------------------------
__global__ __launch_bounds__(256, 2) void ms_fused(
    const uint16_t* __restrict__ xaf,
    const uint16_t* __restrict__ xbf,
    _Float16* __restrict__ nump,       // [4][256][8192] f16 partial slabs
    float* __restrict__ csp)           // [8][8192] f32 partial slices
{
  __shared__ __attribute__((aligned(16))) uint16_t XT[2][16384];  // 64KB stage
  __shared__ __attribute__((aligned(16))) uint16_t Ps[2][4096];   // 2x8KB dbuf

  const int tid  = threadIdx.x;
  const int w    = tid >> 6;
  const int lane = tid & 63;
  const int l31  = lane & 31;
  const int g    = lane >> 5;
  const int bid  = blockIdx.x;
  const int mt   = (bid & 1) | ((bid >> 3) << 1);   // 0..127
  const int q    = (bid >> 1) & 3;                  // n-split 0..3
  const int m0   = mt * 64;
  const int a_sub = w >> 1;                  // S n-sub (0/1)
  const int b_sub = w & 1;                   // S m-sub (0/1)

  const char* xafc = (const char*)xaf;
  const char* xbfc = (const char*)xbf;
  char*       XTc  = (char*)XT;
  char*       Psc  = (char*)Ps;

  // Xm B-fragments resident (64 VGPRs), one-time coalesced load
  bf16x8 Bm[16];
  {
    const char* bp = xafc + (size_t)(m0 / 32 + b_sub) * 16384 + g * 512 + l31 * 16;
    #pragma unroll
    for (int ks = 0; ks < 16; ++ks)
      Bm[ks] = __builtin_bit_cast(bf16x8, *(const int4v*)(bp + ks * 1024));
  }

  f32x16 accO[2][2];
  #pragma unroll
  for (int i = 0; i < 2; ++i)
    #pragma unroll
    for (int j = 0; j < 2; ++j)
      #pragma unroll
      for (int r = 0; r < 16; ++r) accO[i][j][r] = 0.0f;
  float csacc = 0.0f;

  const int mloc = 32 * b_sub + l31;
  const int l7   = l31 & 7;
  const int j0   = q * 32;                   // first n-tile index

  // prologue: stage tile j0 into XT[0] (identity copy, 8x 16B per thread)
  {
    const char* src = xafc + (size_t)j0 * 32768;
    #pragma unroll
    for (int r = 0; r < 8; ++r)
      dma16(src + tid * 16 + r * 4096, XTc + tid * 16 + r * 4096);
  }
  __syncthreads();   // one-time full drain; XT[0] ready

  bf16x8 XfE[2][4], XfO[2][4];   // ping-pong PV A-frag buffers

// body T_: cur=CUR_ (=T_&1), loads Xf(T_) into XF_LD, PV(T_-1) uses XF_USE
#define MS_BODY(T_, CUR_, XF_LD, XF_USE, DO_PV)                               \
  {                                                                           \
    const int jt_ = j0 + (T_);                                                \
    char*       psW_ = Psc + (CUR_) * 8192;                                   \
    const char* psR_ = Psc + ((CUR_) ^ 1) * 8192;                             \
    /* issue DMA(t+1) -> XT[cur^1] (freed at bar(t-1)) */                     \
    if ((T_) < 31) {                                                          \
      const char* src_ = xafc + (size_t)(jt_ + 1) * 32768;                    \
      _Pragma("unroll")                                                       \
      for (int r = 0; r < 8; ++r)                                             \
        dma16(src_ + tid * 16 + r * 4096,                                     \
              XTc + ((CUR_) ^ 1) * 32768 + tid * 16 + r * 4096);              \
    }                                                                         \
    /* issue Xf(t) (consumed by PV in body t+1) */                            \
    {                                                                         \
      const int n0_ = jt_ * 64;                                               \
      _Pragma("unroll")                                                       \
      for (int t2 = 0; t2 < 2; ++t2) {                                        \
        const char* xp_ = xbfc + (size_t)(2 * w + t2) * 524288 +              \
                          (size_t)(n0_ >> 3) * 512 + g * 512 + l31 * 16;      \
        _Pragma("unroll")                                                     \
        for (int ks = 0; ks < 4; ++ks)                                        \
          XF_LD[t2][ks] =                                                     \
              __builtin_bit_cast(bf16x8, *(const int4v*)(xp_ + ks * 1024));   \
      }                                                                       \
    }                                                                         \
    /* VMEM pinned above this point; ALU/MFMA/DS may cross freely */          \
    __builtin_amdgcn_sched_barrier(0x38F);                                    \
    /* ---- S(t) = Xn^T Xm from XT[cur] (conflict-free b128) ---- */          \
    f32x16 s;                                                                 \
    _Pragma("unroll")                                                         \
    for (int r = 0; r < 16; ++r) s[r] = 0.0f;                                 \
    {                                                                         \
      const char* ap_ = XTc + (CUR_) * 32768 + a_sub * 16384 + g * 512 +      \
                        l31 * 16;                                             \
      _Pragma("unroll")                                                       \
      for (int ks = 0; ks < 16; ++ks) {                                       \
        bf16x8 A = __builtin_bit_cast(bf16x8,                                 \
                                      *(const int4v*)(ap_ + ks * 1024));      \
        s = __builtin_amdgcn_mfma_f32_32x32x16_bf16(A, Bm[ks], s, 0, 0, 0);   \
      }                                                                       \
    }                                                                         \
    /* ---- PV(t-1): O += Xn(t-1) * P(t-1) ---- */                            \
    if (DO_PV) {                                                              \
      _Pragma("unroll")                                                       \
      for (int ks = 0; ks < 4; ++ks) {                                        \
        bf16x8 Bp[2];                                                         \
        _Pragma("unroll")                                                     \
        for (int mm = 0; mm < 2; ++mm) {                                      \
          int mrow = 32 * mm + l31;                                           \
          int p = (2 * ks + g) ^ l7;                                          \
          Bp[mm] = __builtin_bit_cast(bf16x8,                                 \
              *(const int4v*)(psR_ + mrow * 128 + p * 16));                   \
        }                                                                     \
        _Pragma("unroll")                                                     \
        for (int t2 = 0; t2 < 2; ++t2) {                                      \
          accO[t2][0] = __builtin_amdgcn_mfma_f32_32x32x16_bf16(              \
              XF_USE[t2][ks], Bp[0], accO[t2][0], 0, 0, 0);                   \
          accO[t2][1] = __builtin_amdgcn_mfma_f32_32x32x16_bf16(              \
              XF_USE[t2][ks], Bp[1], accO[t2][1], 0, 0, 0);                   \
        }                                                                     \
      }                                                                       \
    }                                                                         \
    /* ---- exp(t) -> Ps[cur]: e^(6s) = v_exp_f32(8.6562*s), no libm ---- */  \
    _Pragma("unroll")                                                         \
    for (int k = 0; k < 4; ++k) {                                             \
      float a0 = 8.65617024533378f * s[4 * k + 0];                            \
      float a1 = 8.65617024533378f * s[4 * k + 1];                            \
      float a2 = 8.65617024533378f * s[4 * k + 2];                            \
      float a3 = 8.65617024533378f * s[4 * k + 3];                            \
      float e0, e1, e2, e3;                                                   \
      asm("v_exp_f32 %0, %1" : "=v"(e0) : "v"(a0));                           \
      asm("v_exp_f32 %0, %1" : "=v"(e1) : "v"(a1));                           \
      asm("v_exp_f32 %0, %1" : "=v"(e2) : "v"(a2));                           \
      asm("v_exp_f32 %0, %1" : "=v"(e3) : "v"(a3));                           \
      csacc += (e0 + e1) + (e2 + e3);                                         \
      uint32_t lo, hi;                                                        \
      asm("v_cvt_pk_bf16_f32 %0, %1, %2" : "=v"(lo) : "v"(e0), "v"(e1));      \
      asm("v_cvt_pk_bf16_f32 %0, %1, %2" : "=v"(hi) : "v"(e2), "v"(e3));      \
      int p = (4 * a_sub + k) ^ (mloc & 7);                                   \
      *(uint64_t*)(psW_ + mloc * 128 + p * 16 + 8 * g) =                      \
          ((uint64_t)hi << 32) | lo;                                          \
    }                                                                         \
    /* bar(t): Ps[cur] visible; DMA(t+1) (oldest 8) done; Xf(t) flies */      \
    asm volatile("s_waitcnt vmcnt(8) lgkmcnt(0)" ::: "memory");               \
    __builtin_amdgcn_s_barrier();                                             \
  }

  MS_BODY(0, 0, XfE, XfO, false)
  for (int tp = 0; tp < 15; ++tp) {
    const int tb = 2 * tp;
    MS_BODY(tb + 1, 1, XfO, XfE, true)
    MS_BODY(tb + 2, 0, XfE, XfO, true)
  }
  MS_BODY(31, 1, XfO, XfE, true)
#undef MS_BODY

  // ---- final PV(31): P from Ps[1] (written by body 31), Xf(31)=XfO ----
  {
    const char* psR = Psc + 8192;
    #pragma unroll
    for (int ks = 0; ks < 4; ++ks) {
      bf16x8 Bp[2];
      #pragma unroll
      for (int mm = 0; mm < 2; ++mm) {
        int mrow = 32 * mm + l31;
        int p = (2 * ks + g) ^ l7;
        Bp[mm] = __builtin_bit_cast(bf16x8,
            *(const int4v*)(psR + mrow * 128 + p * 16));
      }
      #pragma unroll
      for (int t2 = 0; t2 < 2; ++t2) {
        accO[t2][0] = __builtin_amdgcn_mfma_f32_32x32x16_bf16(XfO[t2][ks], Bp[0], accO[t2][0], 0,0,0);
        accO[t2][1] = __builtin_amdgcn_mfma_f32_32x32x16_bf16(XfO[t2][ks], Bp[1], accO[t2][1], 0,0,0);
      }
    }
  }

  // ---- epilogue: PLAIN f16 stores into private q-slab (single writer) ----
  csacc += __shfl_xor(csacc, 32, 64);
  if (g == 0) csp[(size_t)(2 * q + a_sub) * NPTS + m0 + mloc] = csacc;
  {
    _Float16* np = nump + (size_t)q * (DFEAT * (size_t)NPTS);
    #pragma unroll
    for (int t2 = 0; t2 < 2; ++t2)
      #pragma unroll
      for (int mm = 0; mm < 2; ++mm)
        #pragma unroll
        for (int r = 0; r < 16; ++r) {
          int drow = 32 * (2 * w + t2) + (r & 3) + 8 * (r >> 2) + 4 * g;
          int mg   = m0 + 32 * mm + l31;
          np[(size_t)drow * NPTS + mg] = (_Float16)accO[t2][mm][r];
        }
  }
}

// ---------------------------------------------------------------------------
// Combine. mode1: v = (sum of 4 f16 num_p slabs) * (1 / sum of 8 cs_p)
//          -> yout ; mode0: v = srcX (initial fp32 X).
// 8-wide lanes: 16B f16x8 slab loads, f32 summation, 32B f32x8 yout store.
// last=1: yout only (skip LDS transpose + frag emission entirely).
// ---------------------------------------------------------------------------
__global__ __launch_bounds__(256) void ms_combine(
    const float* __restrict__ srcX, const _Float16* __restrict__ nh,
    const float* __restrict__ csp, float* __restrict__ yout,
    uint16_t* __restrict__ xaf, uint16_t* __restrict__ xbf,
    const int mode, const int last)
{
  __shared__ uint16_t T[64][66];
  const int tid = threadIdx.x;
  const int n0 = blockIdx.x * 64;
  const int d0 = blockIdx.y * 64;

  f32x8 rinv;
  if (mode) {
    const int mq = tid & 7;
    f32x8 c = *(const f32x8*)(csp + n0 + mq * 8);
    #pragma unroll
    for (int s2 = 1; s2 < 8; ++s2)
      c += *(const f32x8*)(csp + (size_t)s2 * NPTS + n0 + mq * 8);
    #pragma unroll
    for (int k = 0; k < 8; ++k) rinv[k] = 1.0f / c[k];
  }

  #pragma unroll
  for (int i = 0; i < 2; ++i) {
    int e  = tid + i * 256;              // 0..511: (dl, mq) 8-float slot
    int dl = e >> 3, mq = e & 7;
    size_t idx = (size_t)(d0 + dl) * NPTS + n0 + mq * 8;
    f32x8 v;
    if (mode) {
      const size_t SS = (size_t)DFEAT * NPTS;   // slab stride (elements)
      f16x8 a0 = *(const f16x8*)(nh + idx);
      f16x8 a1 = *(const f16x8*)(nh + idx + SS);
      f16x8 a2 = *(const f16x8*)(nh + idx + 2 * SS);
      f16x8 a3 = *(const f16x8*)(nh + idx + 3 * SS);
      v = (__builtin_convertvector(a0, f32x8) +
           __builtin_convertvector(a1, f32x8)) +
          (__builtin_convertvector(a2, f32x8) +
           __builtin_convertvector(a3, f32x8));
      v *= rinv;
      *(f32x8*)(yout + idx) = v;
    } else {
      v = *(const f32x8*)(srcX + idx);
    }
    if (!last) {
      #pragma unroll
      for (int k = 0; k < 8; ++k) T[dl][mq * 8 + k] = f2bf(v[k]);
    }
  }
  if (last) return;
  __syncthreads();

  char* xafc = (char*)xaf;
  char* xbfc = (char*)xbf;
  // xaf chunks: (nb, s, lane) -> T[s*8 + j][nb*32+lane]
  #pragma unroll
  for (int i = 0; i < 2; ++i) {
    int c  = tid + i * 256;
    int nb = c >> 8, s2 = (c >> 5) & 7, ln = c & 31;
    union { uint32_t u[4]; int4v v; } pk;
    #pragma unroll
    for (int k = 0; k < 4; ++k) {
      uint32_t lo = T[s2 * 8 + 2 * k][nb * 32 + ln];
      uint32_t hi = T[s2 * 8 + 2 * k + 1][nb * 32 + ln];
      pk.u[k] = lo | (hi << 16);
    }
    *(int4v*)(xafc + (size_t)(n0 / 32 + nb) * 16384 +
              (size_t)(d0 / 8 + s2) * 512 + ln * 16) = pk.v;
  }
  // xbf chunks: (db, u, lane) -> T[db*32+lane][u*8 + j]  (row-contiguous)
  #pragma unroll
  for (int i = 0; i < 2; ++i) {
    int c  = tid + i * 256;
    int db = c >> 8, uu = (c >> 5) & 7, ln = c & 31;
    const uint16_t* tr = &T[db * 32 + ln][uu * 8];
    union { uint32_t u[4]; int4v v; } pk;
    #pragma unroll
    for (int k = 0; k < 4; ++k)
      pk.u[k] = (uint32_t)tr[2 * k] | ((uint32_t)tr[2 * k + 1] << 16);
    *(int4v*)(xbfc + (size_t)(d0 / 32 + db) * 524288 +
              (size_t)(n0 / 8 + uu) * 512 + ln * 16) = pk.v;
  }
}

extern "C" void kernel_launch(void* const* d_in, const int* in_sizes, int n_in,
                              void* d_out, int out_size, void* d_ws, size_t ws_size,
                              hipStream_t stream)
{
  (void)in_sizes; (void)n_in; (void)out_size; (void)ws_size;
  const float* X = (const float*)d_in[0];
  float* out = (float*)d_out;
  char* ws = (char*)d_ws;
  // ws: [0,4M) xaf ; [4M,8M) xbf ; [8M,24M) num_p[4] f16 ; [24M,+256K) cs_p[8]
  uint16_t* xaf  = (uint16_t*)(ws);
  uint16_t* xbf  = (uint16_t*)(ws + (4u << 20));
  _Float16* nump = (_Float16*)(ws + (8u << 20));
  float*    csp  = (float*)   (ws + (24u << 20));

  // no zeroing needed: every partial element is written by exactly one
  // thread each iteration before combine reads it.

  dim3 cgrid(NPTS / 64, DFEAT / 64);
  ms_combine<<<cgrid, 256, 0, stream>>>(X, nullptr, nullptr, nullptr,
                                        xaf, xbf, 0, 0);
  for (int it = 0; it < 3; ++it) {
    ms_fused<<<512, 256, 0, stream>>>(xaf, xbf, nump, csp);
    ms_combine<<<cgrid, 256, 0, stream>>>(nullptr, nump, csp,
                                          out + (size_t)it * DFEAT * NPTS,
                                          xaf, xbf, 1, it == 2);
  }
}